// Round 4
// baseline (2593.355 us; speedup 1.0000x reference)
//
#include <hip/hip_runtime.h>
#include <hip/hip_bf16.h>

typedef __bf16 bf16x8 __attribute__((ext_vector_type(8)));
typedef __bf16 bf16x4 __attribute__((ext_vector_type(4)));
typedef float  f32x4  __attribute__((ext_vector_type(4)));

// ---------------- cast fp32 -> bf16, 8 elems/thread ----------------
__global__ void cast_f32_bf16(const float* __restrict__ src, __bf16* __restrict__ dst, int n8) {
    int i = blockIdx.x * 256 + threadIdx.x;
    if (i >= n8) return;
    const float4* s = (const float4*)src;
    float4 a = s[2 * i], b = s[2 * i + 1];
    bf16x8 o;
    o[0] = (__bf16)a.x; o[1] = (__bf16)a.y; o[2] = (__bf16)a.z; o[3] = (__bf16)a.w;
    o[4] = (__bf16)b.x; o[5] = (__bf16)b.y; o[6] = (__bf16)b.z; o[7] = (__bf16)b.w;
    ((bf16x8*)dst)[i] = o;
}

// ---------------- GEMM: C[M][N] = A[M][K] * Bm[N][K]^T ----------------
// 128x128 tile, BK=64, reg-prefetch next tile (T14): loads never sit between barriers.
template <int OUT_BF16>
__global__ __launch_bounds__(256, 3)
void gemm_bt(const __bf16* __restrict__ A, const __bf16* __restrict__ Bm,
             void* __restrict__ Cout, int M, int N, int K) {
    __shared__ __bf16 As[128 * 64];
    __shared__ __bf16 Bs[128 * 64];
    const int tid = threadIdx.x;
    const int lane = tid & 63, wid = tid >> 6;
    const int g = lane >> 4, lq = lane & 15;
    const int wr = wid >> 1, wc = wid & 1;
    const size_t brow = (size_t)blockIdx.y * 128, bcol = (size_t)blockIdx.x * 128;
    f32x4 acc[4][4] = {};
    const int nkt = K >> 6;

    const int srow = (tid * 16) >> 7 & 127;   // staging row from flat layout
    int4 va[4], vb[4];
#pragma unroll
    for (int is = 0; is < 4; ++is) {
        int flat = is * 4096 + tid * 16;
        int row  = flat >> 7, colb = flat & 127;
        va[is] = *(const int4*)((const char*)A + ((brow + row) * (size_t)K) * 2 + colb);
        vb[is] = *(const int4*)((const char*)Bm + ((bcol + row) * (size_t)K) * 2 + colb);
    }
    (void)srow;

    for (int kt = 0; kt < nkt; ++kt) {
        __syncthreads();
#pragma unroll
        for (int is = 0; is < 4; ++is) {
            int flat = is * 4096 + tid * 16;
            int row  = flat >> 7, colb = flat & 127;
            int sw   = colb ^ ((row & 7) << 4);
            *(int4*)((char*)As + row * 128 + sw) = va[is];
            *(int4*)((char*)Bs + row * 128 + sw) = vb[is];
        }
        if (kt + 1 < nkt) {
#pragma unroll
            for (int is = 0; is < 4; ++is) {
                int flat = is * 4096 + tid * 16;
                int row  = flat >> 7, colb = flat & 127;
                va[is] = *(const int4*)((const char*)A + ((brow + row) * (size_t)K + (size_t)(kt + 1) * 64) * 2 + colb);
                vb[is] = *(const int4*)((const char*)Bm + ((bcol + row) * (size_t)K + (size_t)(kt + 1) * 64) * 2 + colb);
            }
        }
        __syncthreads();
#pragma unroll
        for (int ks = 0; ks < 2; ++ks) {
            bf16x8 af[4], bfr[4];
            const int kb = ks * 64 + g * 16;
#pragma unroll
            for (int i = 0; i < 4; ++i) {
                int row = wr * 64 + i * 16 + lq;
                af[i] = *(const bf16x8*)((const char*)As + row * 128 + (kb ^ ((row & 7) << 4)));
            }
#pragma unroll
            for (int j = 0; j < 4; ++j) {
                int row = wc * 64 + j * 16 + lq;
                bfr[j] = *(const bf16x8*)((const char*)Bs + row * 128 + (kb ^ ((row & 7) << 4)));
            }
            __builtin_amdgcn_s_setprio(1);
#pragma unroll
            for (int i = 0; i < 4; ++i)
#pragma unroll
                for (int j = 0; j < 4; ++j)
                    acc[i][j] = __builtin_amdgcn_mfma_f32_16x16x32_bf16(af[i], bfr[j], acc[i][j], 0, 0, 0);
            __builtin_amdgcn_s_setprio(0);
        }
    }
#pragma unroll
    for (int i = 0; i < 4; ++i) {
#pragma unroll
        for (int r = 0; r < 4; ++r) {
            size_t row = brow + wr * 64 + i * 16 + g * 4 + r;
#pragma unroll
            for (int j = 0; j < 4; ++j) {
                size_t col = bcol + wc * 64 + j * 16 + lq;
                float v = acc[i][j][r];
                if (OUT_BF16) ((__bf16*)Cout)[row * N + col] = (__bf16)v;
                else          ((float*)Cout)[row * N + col] = v;
            }
        }
    }
}

// ---------------- V transpose: qkv V-part -> vt[(b*8+kh)*128+d][t] ----------------
__global__ __launch_bounds__(256)
void transpose_v(const __bf16* __restrict__ qkv, __bf16* __restrict__ vt) {
    constexpr int S = 2048, QKVN = 6144;
    __shared__ __bf16 tile[64][72];
    const int tt = blockIdx.x;
    const int yz = blockIdx.y;
    const int dh = yz & 1, bkh = yz >> 1;
    const int b = bkh >> 3, kh = bkh & 7;
    const int tid = threadIdx.x;
#pragma unroll
    for (int i = 0; i < 2; ++i) {
        int flat = i * 2048 + tid * 8;
        int r = flat >> 6, c0 = flat & 63;
        const __bf16* src = qkv + ((size_t)b * S + tt * 64 + r) * QKVN + 5120 + kh * 128 + dh * 64 + c0;
        *(bf16x8*)&tile[r][c0] = *(const bf16x8*)src;
    }
    __syncthreads();
#pragma unroll
    for (int i = 0; i < 2; ++i) {
        int flat = i * 2048 + tid * 8;
        int d = flat >> 6, t0 = flat & 63;
        bf16x8 pk;
#pragma unroll
        for (int e = 0; e < 8; ++e) pk[e] = tile[t0 + e][d];
        __bf16* dst = vt + ((size_t)(b * 8 + kh) * 128 + dh * 64 + d) * S + tt * 64 + t0;
        *(bf16x8*)dst = pk;
    }
}

// ---------------- flash attention v4 (causal, GQA) ----------------
// 64 q-rows/block (4 waves x 16). KVBLK=64. K AND V staged in LDS with reg-prefetch
// (T14). Swapped QK^T; base-2 softmax; defer-max (T13); per-lane partial l.
__global__ __launch_bounds__(256, 3)
void attn_kernel(const __bf16* __restrict__ qkv, const __bf16* __restrict__ vt,
                 __bf16* __restrict__ outb) {
    constexpr int S = 2048, D = 128, QKVN = 6144;
    const int qt = 31 - (int)blockIdx.y;                 // heavy blocks first
    const int bh = blockIdx.x;
    const int b = bh >> 5, h = bh & 31;
    const int kh = h >> 2;
    const int tid = threadIdx.x, lane = tid & 63, w = tid >> 6;
    const int g = lane >> 4, lq = lane & 15;

    __shared__ __bf16 Ks[64 * 128];          // [t][d], rows 256B, XOR (row&15)<<4
    __shared__ __bf16 Vs[128 * 64];          // [d][t], rows 128B, XOR (d&7)<<4
    __shared__ char   PsRaw[4][16 * 152];    // per-wave P rows, stride 152B

    const int wqmin = qt * 64 + w * 16;
    const int qg = wqmin + lq;

    const __bf16* qrow = qkv + ((size_t)(b * S) + wqmin + lq) * QKVN + h * D;
    bf16x8 qf[4];
#pragma unroll
    for (int ks = 0; ks < 4; ++ks) qf[ks] = *(const bf16x8*)(qrow + ks * 32 + g * 8);

    const char* kbase = (const char*)qkv + ((size_t)(b * S) * QKVN + 4096 + kh * D) * 2;
    const char* vbase = (const char*)vt + ((size_t)(b * 8 + kh) * D * S) * 2;

    f32x4 acc[8] = {};
    float m_r = -1e30f, l_p = 0.f;
    const float scale2 = 0.12753102494f;     // (1/sqrt(128)) * log2(e)

    const int krow0 = tid >> 4;              // 0..15  (K stage: row, 16B col)
    const int kcolb = (tid & 15) * 16;
    const int vrow0 = tid >> 3;              // 0..31  (V stage: d row, 16B col)
    const int vcolb = (tid & 7) * 16;

    int4 pk[4], pv[4];
#pragma unroll
    for (int is = 0; is < 4; ++is) {
        pk[is] = *(const int4*)(kbase + (size_t)(is * 16 + krow0) * QKVN * 2 + kcolb);
        pv[is] = *(const int4*)(vbase + (size_t)(is * 32 + vrow0) * S * 2 + vcolb);
    }

    char* ps = &PsRaw[w][0];

    for (int kt = 0; kt <= qt; ++kt) {
        __syncthreads();                     // previous tile's reads done
#pragma unroll
        for (int is = 0; is < 4; ++is) {
            int row = is * 16 + krow0;
            *(int4*)((char*)Ks + row * 256 + (kcolb ^ ((row & 15) << 4))) = pk[is];
            int d = is * 32 + vrow0;
            *(int4*)((char*)Vs + d * 128 + (vcolb ^ ((d & 7) << 4))) = pv[is];
        }
        if (kt < qt) {                       // prefetch next K/V tile under compute
#pragma unroll
            for (int is = 0; is < 4; ++is) {
                pk[is] = *(const int4*)(kbase + (size_t)((kt + 1) * 64 + is * 16 + krow0) * QKVN * 2 + kcolb);
                pv[is] = *(const int4*)(vbase + ((size_t)(is * 32 + vrow0) * S + (kt + 1) * 64) * 2 + vcolb);
            }
        }
        __syncthreads();                     // tile ready

        // ---- QK^T (swapped): sc[tb][r] = S2[q=lq][t = kt*64 + tb*16 + g*4 + r]
        f32x4 sc[4];
        __builtin_amdgcn_s_setprio(1);
#pragma unroll
        for (int tb = 0; tb < 4; ++tb) {
            f32x4 s = {0.f, 0.f, 0.f, 0.f};
            const int trow = tb * 16 + lq;
            const int rsw = (trow & 15) << 4;
#pragma unroll
            for (int ks = 0; ks < 4; ++ks) {
                bf16x8 kf = *(const bf16x8*)((const char*)Ks + trow * 256 + ((ks * 64 + g * 16) ^ rsw));
                s = __builtin_amdgcn_mfma_f32_16x16x32_bf16(kf, qf[ks], s, 0, 0, 0);
            }
            sc[tb] = s;
        }
        __builtin_amdgcn_s_setprio(0);

        // ---- softmax (base-2, defer-max, per-lane partial l)
        float p[16];
        float rowmax = -1e30f;
        const bool domask = (kt == qt);
#pragma unroll
        for (int tb = 0; tb < 4; ++tb)
#pragma unroll
            for (int r = 0; r < 4; ++r) {
                float sv = sc[tb][r] * scale2;
                if (domask) {
                    int tg = kt * 64 + tb * 16 + g * 4 + r;
                    sv = (tg <= qg) ? sv : -1e30f;
                }
                p[tb * 4 + r] = sv;
                rowmax = fmaxf(rowmax, sv);
            }
        rowmax = fmaxf(rowmax, __shfl_xor(rowmax, 16));
        rowmax = fmaxf(rowmax, __shfl_xor(rowmax, 32));
        if (!__all(rowmax - m_r <= 11.0f)) { // rare rescale (T13, log2 domain)
            float m_new = fmaxf(m_r, rowmax);
            float alpha = exp2f(m_r - m_new);
            l_p *= alpha;
#pragma unroll
            for (int r = 0; r < 4; ++r) {
                float ar = __shfl(alpha, g * 4 + r);
#pragma unroll
                for (int nb = 0; nb < 8; ++nb) acc[nb][r] *= ar;
            }
            m_r = m_new;
        }
        float lsum = 0.f;
#pragma unroll
        for (int i = 0; i < 16; ++i) {
            float e = exp2f(p[i] - m_r);
            p[i] = e;
            lsum += e;
        }
        l_p += lsum;

        // ---- P -> per-wave LDS (row lq, byte col = 2*t)
#pragma unroll
        for (int tb = 0; tb < 4; ++tb) {
            bf16x4 pkv;
#pragma unroll
            for (int r = 0; r < 4; ++r) pkv[r] = (__bf16)p[tb * 4 + r];
            *(bf16x4*)(ps + lq * 152 + tb * 32 + g * 8) = pkv;
        }

        // ---- PV: A = P (Ps), B = V^T rows from Vs (LDS)
        __builtin_amdgcn_s_setprio(1);
#pragma unroll
        for (int ks = 0; ks < 2; ++ks) {
            bf16x8 pa = *(const bf16x8*)(ps + lq * 152 + ks * 64 + g * 16);
#pragma unroll
            for (int nb = 0; nb < 8; ++nb) {
                int d = nb * 16 + lq;
                bf16x8 vf = *(const bf16x8*)((const char*)Vs + d * 128 + ((ks * 64 + g * 16) ^ ((d & 7) << 4)));
                acc[nb] = __builtin_amdgcn_mfma_f32_16x16x32_bf16(pa, vf, acc[nb], 0, 0, 0);
            }
        }
        __builtin_amdgcn_s_setprio(0);
    }

    // ---- epilogue: reduce l across g-groups, normalize, store
    l_p += __shfl_xor(l_p, 16);
    l_p += __shfl_xor(l_p, 32);
    float rl = 1.f / l_p;
#pragma unroll
    for (int r = 0; r < 4; ++r) {
        float rr = __shfl(rl, g * 4 + r);
        size_t row = (size_t)(b * S) + wqmin + g * 4 + r;
        __bf16* orow = outb + row * 4096 + h * D;
#pragma unroll
        for (int nb = 0; nb < 8; ++nb)
            orow[nb * 16 + lq] = (__bf16)(acc[nb][r] * rr);
    }
}

// ---------------- launch ----------------
extern "C" void kernel_launch(void* const* d_in, const int* in_sizes, int n_in,
                              void* d_out, int out_size, void* d_ws, size_t ws_size,
                              hipStream_t stream) {
    (void)in_sizes; (void)n_in; (void)out_size; (void)ws_size;
    const float* q       = (const float*)d_in[0];
    const float* w_qkv   = (const float*)d_in[1];
    const float* w_dense = (const float*)d_in[2];
    float* out = (float*)d_out;
    char* ws = (char*)d_ws;

    __bf16* qbf      = (__bf16*)(ws);
    __bf16* wqkvbf   = (__bf16*)(ws + 33554432ULL);
    __bf16* wdensebf = (__bf16*)(ws + 83886080ULL);
    __bf16* qkvbf    = (__bf16*)(ws + 117440512ULL);
    __bf16* vtbf     = (__bf16*)(ws + 167772160ULL);
    __bf16* attnbf   = (__bf16*)(ws + 176160768ULL);

    cast_f32_bf16<<<8192, 256, 0, stream>>>(q, qbf, 2097152);
    cast_f32_bf16<<<12288, 256, 0, stream>>>(w_qkv, wqkvbf, 3145728);
    cast_f32_bf16<<<8192, 256, 0, stream>>>(w_dense, wdensebf, 2097152);

    gemm_bt<1><<<dim3(48, 32), 256, 0, stream>>>(qbf, wqkvbf, (void*)qkvbf, 4096, 6144, 4096);
    transpose_v<<<dim3(32, 32), 256, 0, stream>>>(qkvbf, vtbf);
    attn_kernel<<<dim3(64, 32), 256, 0, stream>>>(qkvbf, vtbf, attnbf);
    gemm_bt<0><<<dim3(32, 32), 256, 0, stream>>>(attnbf, wdensebf, (void*)out, 4096, 4096, 4096);
}

// Round 5
// 813.025 us; speedup vs baseline: 3.1898x; 3.1898x over previous
//
#include <hip/hip_runtime.h>
#include <hip/hip_bf16.h>

typedef __bf16 bf16x8 __attribute__((ext_vector_type(8)));
typedef __bf16 bf16x4 __attribute__((ext_vector_type(4)));
typedef float  f32x4  __attribute__((ext_vector_type(4)));

// ---------------- cast fp32 -> bf16, 8 elems/thread ----------------
__global__ void cast_f32_bf16(const float* __restrict__ src, __bf16* __restrict__ dst, int n8) {
    int i = blockIdx.x * 256 + threadIdx.x;
    if (i >= n8) return;
    const float4* s = (const float4*)src;
    float4 a = s[2 * i], b = s[2 * i + 1];
    bf16x8 o;
    o[0] = (__bf16)a.x; o[1] = (__bf16)a.y; o[2] = (__bf16)a.z; o[3] = (__bf16)a.w;
    o[4] = (__bf16)b.x; o[5] = (__bf16)b.y; o[6] = (__bf16)b.z; o[7] = (__bf16)b.w;
    ((bf16x8*)dst)[i] = o;
}

// ---------------- GEMM: C[M][N] = A[M][K] * Bm[N][K]^T (R0-proven version) ----------
// 128x128 tile, BK=64, 256 thr (4 waves, 2x2), 16x16x32 bf16 MFMA, 4x4 frags/wave.
// Direct global->LDS staging between barriers (NO reg-prefetch: holding 8 int4 live
// across two barriers spilled to scratch in R4 -> 3GB writes, 6x regression).
template <int OUT_BF16>
__global__ __launch_bounds__(256)
void gemm_bt(const __bf16* __restrict__ A, const __bf16* __restrict__ Bm,
             void* __restrict__ Cout, int M, int N, int K) {
    __shared__ __bf16 As[128 * 64];
    __shared__ __bf16 Bs[128 * 64];
    const int tid = threadIdx.x;
    const int lane = tid & 63, wid = tid >> 6;
    const int g = lane >> 4, lq = lane & 15;
    const int wr = wid >> 1, wc = wid & 1;
    const size_t brow = (size_t)blockIdx.y * 128, bcol = (size_t)blockIdx.x * 128;
    f32x4 acc[4][4] = {};
    const int nkt = K >> 6;

    for (int kt = 0; kt < nkt; ++kt) {
        __syncthreads();
#pragma unroll
        for (int is = 0; is < 4; ++is) {
            int flat = is * 4096 + tid * 16;       // bytes within 16KB tile
            int row  = flat >> 7;                  // 128B per row (64 bf16)
            int colb = flat & 127;
            int sw   = colb ^ ((row & 7) << 4);
            int4 va = *(const int4*)((const char*)A + ((brow + row) * (size_t)K + (size_t)kt * 64) * 2 + colb);
            *(int4*)((char*)As + row * 128 + sw) = va;
            int4 vb = *(const int4*)((const char*)Bm + ((bcol + row) * (size_t)K + (size_t)kt * 64) * 2 + colb);
            *(int4*)((char*)Bs + row * 128 + sw) = vb;
        }
        __syncthreads();
#pragma unroll
        for (int ks = 0; ks < 2; ++ks) {
            bf16x8 af[4], bfr[4];
            const int kb = ks * 64 + g * 16;
#pragma unroll
            for (int i = 0; i < 4; ++i) {
                int row = wr * 64 + i * 16 + lq;
                af[i] = *(const bf16x8*)((const char*)As + row * 128 + (kb ^ ((row & 7) << 4)));
            }
#pragma unroll
            for (int j = 0; j < 4; ++j) {
                int row = wc * 64 + j * 16 + lq;
                bfr[j] = *(const bf16x8*)((const char*)Bs + row * 128 + (kb ^ ((row & 7) << 4)));
            }
#pragma unroll
            for (int i = 0; i < 4; ++i)
#pragma unroll
                for (int j = 0; j < 4; ++j)
                    acc[i][j] = __builtin_amdgcn_mfma_f32_16x16x32_bf16(af[i], bfr[j], acc[i][j], 0, 0, 0);
        }
    }
#pragma unroll
    for (int i = 0; i < 4; ++i) {
#pragma unroll
        for (int r = 0; r < 4; ++r) {
            size_t row = brow + wr * 64 + i * 16 + g * 4 + r;
#pragma unroll
            for (int j = 0; j < 4; ++j) {
                size_t col = bcol + wc * 64 + j * 16 + lq;
                float v = acc[i][j][r];
                if (OUT_BF16) ((__bf16*)Cout)[row * N + col] = (__bf16)v;
                else          ((float*)Cout)[row * N + col] = v;
            }
        }
    }
}

// ---------------- V transpose: qkv V-part -> vt[(b*8+kh)*128+d][t] ----------------
__global__ __launch_bounds__(256)
void transpose_v(const __bf16* __restrict__ qkv, __bf16* __restrict__ vt) {
    constexpr int S = 2048, QKVN = 6144;
    __shared__ __bf16 tile[64][72];
    const int tt = blockIdx.x;
    const int yz = blockIdx.y;
    const int dh = yz & 1, bkh = yz >> 1;
    const int b = bkh >> 3, kh = bkh & 7;
    const int tid = threadIdx.x;
#pragma unroll
    for (int i = 0; i < 2; ++i) {
        int flat = i * 2048 + tid * 8;
        int r = flat >> 6, c0 = flat & 63;
        const __bf16* src = qkv + ((size_t)b * S + tt * 64 + r) * QKVN + 5120 + kh * 128 + dh * 64 + c0;
        *(bf16x8*)&tile[r][c0] = *(const bf16x8*)src;
    }
    __syncthreads();
#pragma unroll
    for (int i = 0; i < 2; ++i) {
        int flat = i * 2048 + tid * 8;
        int d = flat >> 6, t0 = flat & 63;
        bf16x8 pk;
#pragma unroll
        for (int e = 0; e < 8; ++e) pk[e] = tile[t0 + e][d];
        __bf16* dst = vt + ((size_t)(b * 8 + kh) * 128 + dh * 64 + d) * S + tt * 64 + t0;
        *(bf16x8*)dst = pk;
    }
}

// ---------------- flash attention v4 (causal, GQA) ----------------
// 64 q-rows/block (4 waves x 16). KVBLK=64. K AND V staged in LDS with reg-prefetch
// (T14). Swapped QK^T; base-2 softmax; defer-max (T13); per-lane partial l.
__global__ __launch_bounds__(256, 3)
void attn_kernel(const __bf16* __restrict__ qkv, const __bf16* __restrict__ vt,
                 __bf16* __restrict__ outb) {
    constexpr int S = 2048, D = 128, QKVN = 6144;
    const int qt = 31 - (int)blockIdx.y;                 // heavy blocks first
    const int bh = blockIdx.x;
    const int b = bh >> 5, h = bh & 31;
    const int kh = h >> 2;
    const int tid = threadIdx.x, lane = tid & 63, w = tid >> 6;
    const int g = lane >> 4, lq = lane & 15;

    __shared__ __bf16 Ks[64 * 128];          // [t][d], rows 256B, XOR (row&15)<<4
    __shared__ __bf16 Vs[128 * 64];          // [d][t], rows 128B, XOR (d&7)<<4
    __shared__ char   PsRaw[4][16 * 152];    // per-wave P rows, stride 152B

    const int wqmin = qt * 64 + w * 16;
    const int qg = wqmin + lq;

    const __bf16* qrow = qkv + ((size_t)(b * S) + wqmin + lq) * QKVN + h * D;
    bf16x8 qf[4];
#pragma unroll
    for (int ks = 0; ks < 4; ++ks) qf[ks] = *(const bf16x8*)(qrow + ks * 32 + g * 8);

    const char* kbase = (const char*)qkv + ((size_t)(b * S) * QKVN + 4096 + kh * D) * 2;
    const char* vbase = (const char*)vt + ((size_t)(b * 8 + kh) * D * S) * 2;

    f32x4 acc[8] = {};
    float m_r = -1e30f, l_p = 0.f;
    const float scale2 = 0.12753102494f;     // (1/sqrt(128)) * log2(e)

    const int krow0 = tid >> 4;              // 0..15  (K stage: row, 16B col)
    const int kcolb = (tid & 15) * 16;
    const int vrow0 = tid >> 3;              // 0..31  (V stage: d row, 16B col)
    const int vcolb = (tid & 7) * 16;

    int4 pk[4], pv[4];
#pragma unroll
    for (int is = 0; is < 4; ++is) {
        pk[is] = *(const int4*)(kbase + (size_t)(is * 16 + krow0) * QKVN * 2 + kcolb);
        pv[is] = *(const int4*)(vbase + (size_t)(is * 32 + vrow0) * S * 2 + vcolb);
    }

    char* ps = &PsRaw[w][0];

    for (int kt = 0; kt <= qt; ++kt) {
        __syncthreads();                     // previous tile's reads done
#pragma unroll
        for (int is = 0; is < 4; ++is) {
            int row = is * 16 + krow0;
            *(int4*)((char*)Ks + row * 256 + (kcolb ^ ((row & 15) << 4))) = pk[is];
            int d = is * 32 + vrow0;
            *(int4*)((char*)Vs + d * 128 + (vcolb ^ ((d & 7) << 4))) = pv[is];
        }
        if (kt < qt) {                       // prefetch next K/V tile under compute
#pragma unroll
            for (int is = 0; is < 4; ++is) {
                pk[is] = *(const int4*)(kbase + (size_t)((kt + 1) * 64 + is * 16 + krow0) * QKVN * 2 + kcolb);
                pv[is] = *(const int4*)(vbase + ((size_t)(is * 32 + vrow0) * S + (kt + 1) * 64) * 2 + vcolb);
            }
        }
        __syncthreads();                     // tile ready

        // ---- QK^T (swapped): sc[tb][r] = S2[q=lq][t = kt*64 + tb*16 + g*4 + r]
        f32x4 sc[4];
        __builtin_amdgcn_s_setprio(1);
#pragma unroll
        for (int tb = 0; tb < 4; ++tb) {
            f32x4 s = {0.f, 0.f, 0.f, 0.f};
            const int trow = tb * 16 + lq;
            const int rsw = (trow & 15) << 4;
#pragma unroll
            for (int ks = 0; ks < 4; ++ks) {
                bf16x8 kf = *(const bf16x8*)((const char*)Ks + trow * 256 + ((ks * 64 + g * 16) ^ rsw));
                s = __builtin_amdgcn_mfma_f32_16x16x32_bf16(kf, qf[ks], s, 0, 0, 0);
            }
            sc[tb] = s;
        }
        __builtin_amdgcn_s_setprio(0);

        // ---- softmax (base-2, defer-max, per-lane partial l)
        float p[16];
        float rowmax = -1e30f;
        const bool domask = (kt == qt);
#pragma unroll
        for (int tb = 0; tb < 4; ++tb)
#pragma unroll
            for (int r = 0; r < 4; ++r) {
                float sv = sc[tb][r] * scale2;
                if (domask) {
                    int tg = kt * 64 + tb * 16 + g * 4 + r;
                    sv = (tg <= qg) ? sv : -1e30f;
                }
                p[tb * 4 + r] = sv;
                rowmax = fmaxf(rowmax, sv);
            }
        rowmax = fmaxf(rowmax, __shfl_xor(rowmax, 16));
        rowmax = fmaxf(rowmax, __shfl_xor(rowmax, 32));
        if (!__all(rowmax - m_r <= 11.0f)) { // rare rescale (T13, log2 domain)
            float m_new = fmaxf(m_r, rowmax);
            float alpha = exp2f(m_r - m_new);
            l_p *= alpha;
#pragma unroll
            for (int r = 0; r < 4; ++r) {
                float ar = __shfl(alpha, g * 4 + r);
#pragma unroll
                for (int nb = 0; nb < 8; ++nb) acc[nb][r] *= ar;
            }
            m_r = m_new;
        }
        float lsum = 0.f;
#pragma unroll
        for (int i = 0; i < 16; ++i) {
            float e = exp2f(p[i] - m_r);
            p[i] = e;
            lsum += e;
        }
        l_p += lsum;

        // ---- P -> per-wave LDS (row lq, byte col = 2*t)
#pragma unroll
        for (int tb = 0; tb < 4; ++tb) {
            bf16x4 pkv;
#pragma unroll
            for (int r = 0; r < 4; ++r) pkv[r] = (__bf16)p[tb * 4 + r];
            *(bf16x4*)(ps + lq * 152 + tb * 32 + g * 8) = pkv;
        }

        // ---- PV: A = P (Ps), B = V^T rows from Vs (LDS)
        __builtin_amdgcn_s_setprio(1);
#pragma unroll
        for (int ks = 0; ks < 2; ++ks) {
            bf16x8 pa = *(const bf16x8*)(ps + lq * 152 + ks * 64 + g * 16);
#pragma unroll
            for (int nb = 0; nb < 8; ++nb) {
                int d = nb * 16 + lq;
                bf16x8 vf = *(const bf16x8*)((const char*)Vs + d * 128 + ((ks * 64 + g * 16) ^ ((d & 7) << 4)));
                acc[nb] = __builtin_amdgcn_mfma_f32_16x16x32_bf16(pa, vf, acc[nb], 0, 0, 0);
            }
        }
        __builtin_amdgcn_s_setprio(0);
    }

    // ---- epilogue: reduce l across g-groups, normalize, store
    l_p += __shfl_xor(l_p, 16);
    l_p += __shfl_xor(l_p, 32);
    float rl = 1.f / l_p;
#pragma unroll
    for (int r = 0; r < 4; ++r) {
        float rr = __shfl(rl, g * 4 + r);
        size_t row = (size_t)(b * S) + wqmin + g * 4 + r;
        __bf16* orow = outb + row * 4096 + h * D;
#pragma unroll
        for (int nb = 0; nb < 8; ++nb)
            orow[nb * 16 + lq] = (__bf16)(acc[nb][r] * rr);
    }
}

// ---------------- launch ----------------
extern "C" void kernel_launch(void* const* d_in, const int* in_sizes, int n_in,
                              void* d_out, int out_size, void* d_ws, size_t ws_size,
                              hipStream_t stream) {
    (void)in_sizes; (void)n_in; (void)out_size; (void)ws_size;
    const float* q       = (const float*)d_in[0];
    const float* w_qkv   = (const float*)d_in[1];
    const float* w_dense = (const float*)d_in[2];
    float* out = (float*)d_out;
    char* ws = (char*)d_ws;

    __bf16* qbf      = (__bf16*)(ws);
    __bf16* wqkvbf   = (__bf16*)(ws + 33554432ULL);
    __bf16* wdensebf = (__bf16*)(ws + 83886080ULL);
    __bf16* qkvbf    = (__bf16*)(ws + 117440512ULL);
    __bf16* vtbf     = (__bf16*)(ws + 167772160ULL);
    __bf16* attnbf   = (__bf16*)(ws + 176160768ULL);

    cast_f32_bf16<<<8192, 256, 0, stream>>>(q, qbf, 2097152);
    cast_f32_bf16<<<12288, 256, 0, stream>>>(w_qkv, wqkvbf, 3145728);
    cast_f32_bf16<<<8192, 256, 0, stream>>>(w_dense, wdensebf, 2097152);

    gemm_bt<1><<<dim3(48, 32), 256, 0, stream>>>(qbf, wqkvbf, (void*)qkvbf, 4096, 6144, 4096);
    transpose_v<<<dim3(32, 32), 256, 0, stream>>>(qkvbf, vtbf);
    attn_kernel<<<dim3(64, 32), 256, 0, stream>>>(qkvbf, vtbf, attnbf);
    gemm_bt<0><<<dim3(32, 32), 256, 0, stream>>>(attnbf, wdensebf, (void*)out, 4096, 4096, 4096);
}